// Round 10
// baseline (110.756 us; speedup 1.0000x reference)
//
#include <hip/hip_runtime.h>
#include <math.h>

#define HW   3136   // 56*56
#define NC   512    // channels
#define NB   32     // batch
#define KSEL 256    // top-k

typedef float f32x4 __attribute__((ext_vector_type(4)));

// ---------------------------------------------------------------------------
// DIAGNOSTIC ROUND: identical to the proven round-8 structure (81.6 us), but
// reduce_mean_max is launched TWICE (idempotent). dur(this) - 81.6 isolates
// reduce's true per-dispatch cost, splitting the e2e budget between
// reduce vs (topk + gather + gaps) without rocprof per-kernel rows.
// ---------------------------------------------------------------------------

// Kernel 1: per-(b,c) mean+max over HW; desc = mean + max (conv is linear,
// no bias, so conv(avg)+conv(mx) == conv(avg+mx)). One wave per channel row.
__global__ __launch_bounds__(256) void reduce_mean_max(
    const float* __restrict__ x, float* __restrict__ desc)
{
    const int gwave = (blockIdx.x * blockDim.x + threadIdx.x) >> 6; // b*NC + c
    const int lane  = threadIdx.x & 63;

    const f32x4* p = (const f32x4*)(x + (size_t)gwave * HW);
    float s = 0.0f, m = -INFINITY;
#pragma unroll
    for (int i = 0; i < 12; ++i) {          // 12*64 = 768 float4
        f32x4 v = p[lane + i * 64];
        s += (v.x + v.y) + (v.z + v.w);
        m = fmaxf(m, fmaxf(fmaxf(v.x, v.y), fmaxf(v.z, v.w)));
    }
    if (lane < 16) {                        // tail: 784-768
        f32x4 v = p[lane + 768];
        s += (v.x + v.y) + (v.z + v.w);
        m = fmaxf(m, fmaxf(fmaxf(v.x, v.y), fmaxf(v.z, v.w)));
    }
#pragma unroll
    for (int off = 32; off; off >>= 1) {
        s += __shfl_down(s, off, 64);
        m = fmaxf(m, __shfl_down(m, off, 64));
    }
    if (lane == 0) desc[gwave] = s * (1.0f / (float)HW) + m;
}

// Kernel 2: per-batch conv1d + sigmoid + top-K select (proven 512-thread
// rank/ballot version). Ascending-channel compaction == reference argsort.
__global__ __launch_bounds__(512) void score_topk(
    const float* __restrict__ desc, const float* __restrict__ w,
    int* __restrict__ sidx, float* __restrict__ sval)
{
    const int b = blockIdx.x;
    const int c = threadIdx.x;
    __shared__ float s_d[NC + 2];
    __shared__ float s_score[NC];
    __shared__ int   s_wcnt[8];

    if (c == 0) { s_d[0] = 0.0f; s_d[NC + 1] = 0.0f; }
    s_d[c + 1] = desc[b * NC + c];
    __syncthreads();

    const float w0 = w[0], w1 = w[1], w2 = w[2];
    // cross-correlation (lax conv does NOT flip the kernel)
    const float t = s_d[c] * w0 + s_d[c + 1] * w1 + s_d[c + 2] * w2;
    const float score = 1.0f / (1.0f + expf(-t));
    s_score[c] = score;
    __syncthreads();

    int rank = 0;
    for (int j = 0; j < NC; ++j) {
        const float sj = s_score[j];
        rank += (sj > score) || (sj == score && j < c);   // lax.top_k tie-break
    }
    const int flag = (rank < KSEL) ? 1 : 0;

    const unsigned long long bal = __ballot(flag);
    const int wid = c >> 6, lane = c & 63;
    if (lane == 0) s_wcnt[wid] = __popcll(bal);
    __syncthreads();

    if (flag) {
        int pos = __popcll(bal & ((1ULL << lane) - 1ULL));
        for (int wj = 0; wj < wid; ++wj) pos += s_wcnt[wj];
        sidx[b * KSEL + pos] = c;
        sval[b * KSEL + pos] = score;
    }
}

// Kernel 3: gather selected channels, scale; NT loads + NT stores (proven).
__global__ __launch_bounds__(256) void gather_scale(
    const float* __restrict__ x, const int* __restrict__ sidx,
    const float* __restrict__ sval, float* __restrict__ out)
{
    const int bk = blockIdx.x;          // b*KSEL + k
    const int b  = bk >> 8;             // KSEL == 256
    const int ch = sidx[bk];
    const float sv = sval[bk];

    const f32x4* src = (const f32x4*)(x + ((size_t)b * NC + ch) * HW);
    f32x4*       dst = (f32x4*)(out + (size_t)bk * HW);

    const int t = threadIdx.x;
#pragma unroll
    for (int i = 0; i < 3; ++i) {       // 784 = 3*256 + 16
        f32x4 v = __builtin_nontemporal_load(&src[t + i * 256]);
        v.x *= sv; v.y *= sv; v.z *= sv; v.w *= sv;
        __builtin_nontemporal_store(v, &dst[t + i * 256]);
    }
    if (t < 16) {
        f32x4 v = __builtin_nontemporal_load(&src[t + 768]);
        v.x *= sv; v.y *= sv; v.z *= sv; v.w *= sv;
        __builtin_nontemporal_store(v, &dst[t + 768]);
    }
}

extern "C" void kernel_launch(void* const* d_in, const int* in_sizes, int n_in,
                              void* d_out, int out_size, void* d_ws, size_t ws_size,
                              hipStream_t stream)
{
    const float* x = (const float*)d_in[0];   // [32,512,56,56]
    const float* w = (const float*)d_in[1];   // [1,1,3] -> 3 floats
    float* out = (float*)d_out;               // [32,256,56,56]

    // ws layout (floats): desc[16384] | sval[8192] | sidx[8192 i32]
    float* desc = (float*)d_ws;
    float* sval = desc + NB * NC;
    int*   sidx = (int*)(sval + NB * KSEL);

    // DIAGNOSTIC: reduce launched twice (idempotent) to measure its cost by
    // e2e differencing against the 81.6 us single-launch baseline.
    reduce_mean_max<<<(NB * NC) / 4, 256, 0, stream>>>(x, desc);
    reduce_mean_max<<<(NB * NC) / 4, 256, 0, stream>>>(x, desc);

    score_topk<<<NB, NC, 0, stream>>>(desc, w, sidx, sval);

    gather_scale<<<NB * KSEL, 256, 0, stream>>>(x, sidx, sval, out);
}